// Round 5
// baseline (263.208 us; speedup 1.0000x reference)
//
#include <hip/hip_runtime.h>

#define B_N 32768
#define D 512
#define DD (D * D)
#define NLEV 10
#define PAD 64                    // level-segment alignment
#define NHB 128                   // histogram blocks (B_N / 256)
#define MROWS_MAX 34048           // >= 32768 + 10*PAD, /32 divisible
#define WM 32                     // rows per wave tile (and per block)
#define NMT (MROWS_MAX / WM)      // 1064 blocks

typedef unsigned short u16;
typedef short s16x8 __attribute__((ext_vector_type(8)));
typedef u16 u16x8 __attribute__((ext_vector_type(8)));
typedef float f32x4 __attribute__((ext_vector_type(4)));

__device__ __forceinline__ u16 f2bf(float f) {
  union { float f; unsigned u; } v; v.f = f;
  unsigned r = v.u + 0x7fffu + ((v.u >> 16) & 1u);  // RNE
  return (u16)(r >> 16);
}
__device__ __forceinline__ int clampv(int v) {
  return v < 0 ? 0 : (v > NLEV - 1 ? NLEV - 1 : v);
}

// ---- K1: weff-build (blocks 0..1023) UNION hist+perm-fill (blocks 1024..1151)
__global__ void k1(const float* __restrict__ W, const float* __restrict__ lg,
                   const float* __restrict__ attn, const int* __restrict__ val,
                   u16* __restrict__ weff, u16* __restrict__ hist,
                   int* __restrict__ perm) {
  const int t = threadIdx.x;
  if (blockIdx.x < DD / 256) {
    __shared__ float c[NLEV * NLEV];
    if (t < NLEV) {
      float g[NLEV], a[NLEV], mx = -1e30f;
      #pragma unroll
      for (int l = 0; l < NLEV; ++l) {
        g[l] = 1.0f / (1.0f + expf(-lg[l]));
        a[l] = attn[t * NLEV + l];
        mx = fmaxf(mx, a[l]);
      }
      float s = 0.f;
      #pragma unroll
      for (int l = 0; l < NLEV; ++l) { a[l] = expf(a[l] - mx); s += a[l]; }
      float inv = 1.0f / s;
      #pragma unroll
      for (int l = 0; l < NLEV; ++l) {
        float cc = 0.3f * a[l] * inv * g[l];
        if (l == t) cc += 0.7f * g[t];
        c[t * NLEV + l] = cc;
      }
    }
    __syncthreads();
    const int idx = blockIdx.x * 256 + t;
    float w[NLEV];
    #pragma unroll
    for (int l = 0; l < NLEV; ++l) w[l] = W[l * DD + idx];
    #pragma unroll
    for (int v = 0; v < NLEV; ++v) {
      float s = 0.f;
      #pragma unroll
      for (int l = 0; l < NLEV; ++l) s += c[v * NLEV + l] * w[l];
      weff[v * DD + idx] = f2bf(s);
    }
  } else {
    __shared__ int lc[NLEV];
    const int b = blockIdx.x - DD / 256;   // 0..127
    if (t < NLEV) lc[t] = 0;
    __syncthreads();
    const int gid = b * 256 + t;
    atomicAdd(&lc[clampv(val[gid])], 1);
    perm[gid] = -1;
    if (b < (MROWS_MAX - B_N) / 256) perm[B_N + b * 256 + t] = -1;
    __syncthreads();
    if (t < NLEV) hist[b * NLEV + t] = (u16)lc[t];
  }
}

// ---- K2: deterministic counting-sort scatter (prefix over hist table) ------
__global__ void k2(const int* __restrict__ val, const u16* __restrict__ hist,
                   int* __restrict__ perm, int* __restrict__ starts) {
  __shared__ int h[NHB * NLEV];
  __shared__ int st[NLEV + 1];
  __shared__ int cnt[NLEV];
  __shared__ int lc[NLEV];
  const int t = threadIdx.x, b = blockIdx.x;
  for (int i = t; i < NHB * NLEV; i += 256) h[i] = hist[i];
  if (t < NLEV) lc[t] = 0;
  __syncthreads();
  if (t < NLEV) {
    int run = 0;
    for (int bb = 0; bb < NHB; ++bb) {
      int x = h[bb * NLEV + t];
      h[bb * NLEV + t] = run;
      run += x;
    }
    cnt[t] = run;
  }
  __syncthreads();
  if (t == 0) {
    int s = 0;
    for (int v = 0; v < NLEV; ++v) {
      st[v] = s;
      s += (cnt[v] + PAD - 1) & ~(PAD - 1);
    }
    st[NLEV] = s;
  }
  __syncthreads();
  const int gid = b * 256 + t;
  const int v = clampv(val[gid]);
  const int pos = atomicAdd(&lc[v], 1);
  perm[st[v] + h[b * NLEV + v] + pos] = gid;
  if (b == 0 && t <= NLEV) starts[t] = st[t];
}

// ---- K3: zero-LDS, zero-barrier per-wave GEMM ------------------------------
// Each block = 8 fully independent waves sharing a 32-row A tile (L1-hot),
// wave w owns cols [w*64, w*64+64). A frags built per-lane from gathered x
// rows (fp32->bf16 in-reg); B frags loaded per-lane directly from weff
// (L2/L3-resident, 5.2MB) in exact MFMA layout. Fully unrolled K-loop with
// immediate-offset addressing; 1-step register prefetch; no __syncthreads.
__global__ __launch_bounds__(512, 4) void k3(
    const float* __restrict__ x, const u16* __restrict__ weff,
    const int* __restrict__ perm, const int* __restrict__ starts,
    const float* __restrict__ bias, float* __restrict__ out) {
  const int mt = blockIdx.x;
  const int rbase = mt * WM;
  const int Mpad = starts[NLEV];
  if (rbase >= Mpad) return;

  int v = 0;
  #pragma unroll
  for (int i = 1; i < NLEV; ++i) if (rbase >= starts[i]) v = i;

  const int tid = threadIdx.x;
  const int lane = tid & 63, wvi = tid >> 6;   // 8 waves
  const int fm = lane & 15, cbk = lane >> 4;   // frag row/col, k-chunk 0..3
  const int wn = wvi * 64;

  // A row gather (frag rows fm, fm+16 of this 32-row tile)
  const int pr0 = perm[rbase + fm];
  const int pr1 = perm[rbase + 16 + fm];
  const float* a0 = x + (size_t)(pr0 < 0 ? 0 : pr0) * D + cbk * 8;
  const float* a1 = x + (size_t)(pr1 < 0 ? 0 : pr1) * D + cbk * 8;
  // B base: row n = wn + t4*16 + fm, k-bytes cbk*16 within each 32-elem slice
  const u16* wb = weff + (size_t)v * DD + (size_t)(wn + fm) * D + cbk * 8;

  f32x4 acc[2][4];
  #pragma unroll
  for (int m = 0; m < 2; ++m)
    #pragma unroll
    for (int n = 0; n < 4; ++n) acc[m][n] = (f32x4){0.f, 0.f, 0.f, 0.f};

  // prefetch k=0
  f32x4 pa00, pa01, pa10, pa11;
  s16x8 pb0, pb1, pb2, pb3;
  {
    const f32x4* A0 = (const f32x4*)a0;
    const f32x4* A1 = (const f32x4*)a1;
    pa00 = A0[0]; pa01 = A0[1];
    pa10 = A1[0]; pa11 = A1[1];
    pb0 = *(const s16x8*)(wb);
    pb1 = *(const s16x8*)(wb + 16 * D);
    pb2 = *(const s16x8*)(wb + 32 * D);
    pb3 = *(const s16x8*)(wb + 48 * D);
  }

  #pragma unroll
  for (int k = 0; k < D / 32; ++k) {
    // convert current A (data loaded last iter -> latency slack)
    u16x8 t0, t1;
    #pragma unroll
    for (int q = 0; q < 4; ++q) {
      t0[q] = f2bf(pa00[q]); t0[4 + q] = f2bf(pa01[q]);
      t1[q] = f2bf(pa10[q]); t1[4 + q] = f2bf(pa11[q]);
    }
    const s16x8 ca0 = (s16x8)t0, ca1 = (s16x8)t1;
    const s16x8 cb0 = pb0, cb1 = pb1, cb2 = pb2, cb3 = pb3;
    // issue k+1 loads (immediate offsets; no address math in loop)
    if (k + 1 < D / 32) {
      const int off = (k + 1) * 32;
      const f32x4* A0 = (const f32x4*)(a0 + off);
      const f32x4* A1 = (const f32x4*)(a1 + off);
      pa00 = A0[0]; pa01 = A0[1];
      pa10 = A1[0]; pa11 = A1[1];
      pb0 = *(const s16x8*)(wb + off);
      pb1 = *(const s16x8*)(wb + 16 * D + off);
      pb2 = *(const s16x8*)(wb + 32 * D + off);
      pb3 = *(const s16x8*)(wb + 48 * D + off);
    }
    acc[0][0] = __builtin_amdgcn_mfma_f32_16x16x32_bf16(ca0, cb0, acc[0][0], 0, 0, 0);
    acc[0][1] = __builtin_amdgcn_mfma_f32_16x16x32_bf16(ca0, cb1, acc[0][1], 0, 0, 0);
    acc[0][2] = __builtin_amdgcn_mfma_f32_16x16x32_bf16(ca0, cb2, acc[0][2], 0, 0, 0);
    acc[0][3] = __builtin_amdgcn_mfma_f32_16x16x32_bf16(ca0, cb3, acc[0][3], 0, 0, 0);
    acc[1][0] = __builtin_amdgcn_mfma_f32_16x16x32_bf16(ca1, cb0, acc[1][0], 0, 0, 0);
    acc[1][1] = __builtin_amdgcn_mfma_f32_16x16x32_bf16(ca1, cb1, acc[1][1], 0, 0, 0);
    acc[1][2] = __builtin_amdgcn_mfma_f32_16x16x32_bf16(ca1, cb2, acc[1][2], 0, 0, 0);
    acc[1][3] = __builtin_amdgcn_mfma_f32_16x16x32_bf16(ca1, cb3, acc[1][3], 0, 0, 0);
  }

  // Epilogue: C frag col=lane&15, row=(lane>>4)*4+reg; scatter rows via perm
  float bv[4];
  #pragma unroll
  for (int tn = 0; tn < 4; ++tn) bv[tn] = bias[wn + tn * 16 + fm];
  #pragma unroll
  for (int m = 0; m < 2; ++m) {
    #pragma unroll
    for (int r = 0; r < 4; ++r) {
      const int p2 = perm[rbase + m * 16 + cbk * 4 + r];
      if (p2 >= 0) {
        float* o = out + (size_t)p2 * D + wn + fm;
        #pragma unroll
        for (int tn = 0; tn < 4; ++tn)
          o[tn * 16] = acc[m][tn][r] + bv[tn];
      }
    }
  }
}

extern "C" void kernel_launch(void* const* d_in, const int* in_sizes, int n_in,
                              void* d_out, int out_size, void* d_ws, size_t ws_size,
                              hipStream_t stream) {
  const float* x    = (const float*)d_in[0];
  const int*   val  = (const int*)d_in[1];
  const float* W    = (const float*)d_in[2];
  const float* lg   = (const float*)d_in[3];
  const float* attn = (const float*)d_in[4];
  const float* bias = (const float*)d_in[5];
  float* out = (float*)d_out;

  char* ws = (char*)d_ws;
  int* starts = (int*)(ws + 0);          // 11 ints
  u16* hist   = (u16*)(ws + 64);         // 128*10 u16
  int* perm   = (int*)(ws + 2688);       // 34048 ints -> ends 138880
  u16* weff   = (u16*)(ws + 139264);     // 10*512*512 bf16 = 5.24 MB

  k1<<<DD / 256 + NHB, 256, 0, stream>>>(W, lg, attn, val, weff, hist, perm);
  k2<<<NHB, 256, 0, stream>>>(val, hist, perm, starts);
  k3<<<NMT, 512, 0, stream>>>(x, weff, perm, starts, bias, out);
}

// Round 6
// 223.285 us; speedup vs baseline: 1.1788x; 1.1788x over previous
//
#include <hip/hip_runtime.h>

#define B_N 32768
#define D 512
#define DD (D * D)
#define NLEV 10
#define TM 128
#define TN 256
#define BK 32
#define NITER (D / BK)            // 16
#define NHB 128                   // histogram blocks (B_N / 256)
#define MROWS_MAX 34048           // 32768 + 10*128 padding headroom
#define MAX_RT (MROWS_MAX / TM)   // 266

typedef unsigned short u16;
typedef short s16x8 __attribute__((ext_vector_type(8)));
typedef u16 u16x8 __attribute__((ext_vector_type(8)));
typedef float f32x4 __attribute__((ext_vector_type(4)));

__device__ __forceinline__ u16 f2bf(float f) {
  union { float f; unsigned u; } v; v.f = f;
  unsigned r = v.u + 0x7fffu + ((v.u >> 16) & 1u);  // RNE
  return (u16)(r >> 16);
}
__device__ __forceinline__ int clampv(int v) {
  return v < 0 ? 0 : (v > NLEV - 1 ? NLEV - 1 : v);
}

// ---- K1: weff-build (blocks 0..1023) UNION hist+perm-fill (blocks 1024..1151)
__global__ void k1(const float* __restrict__ W, const float* __restrict__ lg,
                   const float* __restrict__ attn, const int* __restrict__ val,
                   u16* __restrict__ weff, u16* __restrict__ hist,
                   int* __restrict__ perm) {
  const int t = threadIdx.x;
  if (blockIdx.x < DD / 256) {
    __shared__ float c[NLEV * NLEV];
    if (t < NLEV) {
      float g[NLEV], a[NLEV], mx = -1e30f;
      #pragma unroll
      for (int l = 0; l < NLEV; ++l) {
        g[l] = 1.0f / (1.0f + expf(-lg[l]));
        a[l] = attn[t * NLEV + l];
        mx = fmaxf(mx, a[l]);
      }
      float s = 0.f;
      #pragma unroll
      for (int l = 0; l < NLEV; ++l) { a[l] = expf(a[l] - mx); s += a[l]; }
      float inv = 1.0f / s;
      #pragma unroll
      for (int l = 0; l < NLEV; ++l) {
        float cc = 0.3f * a[l] * inv * g[l];
        if (l == t) cc += 0.7f * g[t];
        c[t * NLEV + l] = cc;
      }
    }
    __syncthreads();
    const int idx = blockIdx.x * 256 + t;
    float w[NLEV];
    #pragma unroll
    for (int l = 0; l < NLEV; ++l) w[l] = W[l * DD + idx];
    #pragma unroll
    for (int v = 0; v < NLEV; ++v) {
      float s = 0.f;
      #pragma unroll
      for (int l = 0; l < NLEV; ++l) s += c[v * NLEV + l] * w[l];
      weff[v * DD + idx] = f2bf(s);
    }
  } else {
    __shared__ int lc[NLEV];
    const int b = blockIdx.x - DD / 256;   // 0..127
    if (t < NLEV) lc[t] = 0;
    __syncthreads();
    const int gid = b * 256 + t;
    atomicAdd(&lc[clampv(val[gid])], 1);
    perm[gid] = -1;
    if (b < (MROWS_MAX - B_N) / 256) perm[B_N + b * 256 + t] = -1;
    __syncthreads();
    if (t < NLEV) hist[b * NLEV + t] = (u16)lc[t];
  }
}

// ---- K2: deterministic counting-sort scatter (prefix over hist table) ------
__global__ void k2(const int* __restrict__ val, const u16* __restrict__ hist,
                   int* __restrict__ perm, int* __restrict__ starts) {
  __shared__ int h[NHB * NLEV];
  __shared__ int st[NLEV + 1];
  __shared__ int cnt[NLEV];
  __shared__ int lc[NLEV];
  const int t = threadIdx.x, b = blockIdx.x;
  for (int i = t; i < NHB * NLEV; i += 256) h[i] = hist[i];
  if (t < NLEV) lc[t] = 0;
  __syncthreads();
  if (t < NLEV) {
    int run = 0;
    for (int bb = 0; bb < NHB; ++bb) {
      int x = h[bb * NLEV + t];
      h[bb * NLEV + t] = run;
      run += x;
    }
    cnt[t] = run;
  }
  __syncthreads();
  if (t == 0) {
    int s = 0;
    for (int v = 0; v < NLEV; ++v) {
      st[v] = s;
      s += (cnt[v] + TM - 1) & ~(TM - 1);
    }
    st[NLEV] = s;
  }
  __syncthreads();
  const int gid = b * 256 + t;
  const int v = clampv(val[gid]);
  const int pos = atomicAdd(&lc[v], 1);
  perm[st[v] + h[b * NLEV + v] + pos] = gid;
  if (b == 0 && t <= NLEV) starts[t] = st[t];
}

// ---- K3: grouped GEMM, 128x256, triple-buffered, DEEP pipeline -------------
// R4 structure with pipeline slack deepened:
//  * x register FIFO depth 3: issue x(i+3) at iter i, ds_write at i+2
//    (2 iters ~600+cy slack vs HBM ~900cy; R4 had 1 iter -> ~600cy stall/iter)
//  * B gload_lds issued at TOP of iter (targets step i+2, read at i+2)
//  * FIFO-ordered issue (B before x, pinned by asm memory clobber) so the
//    pre-barrier counted wait vmcnt(6) drains exactly B(i-1) while keeping
//    x(i-1), B(i), x(i) in flight across the barrier.
__global__ __launch_bounds__(512, 4) void k3(
    const float* __restrict__ x, const u16* __restrict__ weff,
    const int* __restrict__ perm, const int* __restrict__ starts,
    const float* __restrict__ bias, float* __restrict__ out) {
  __shared__ u16 As[3][TM * BK];   // 3 x 8 KB
  __shared__ u16 Bs[3][TN * BK];   // 3 x 16 KB  -> 72 KB total, 2 blocks/CU

  const int ct = blockIdx.x, rt = blockIdx.y;
  const int Mpad = starts[NLEV];
  if (rt * TM >= Mpad) return;

  int v = 0;
  #pragma unroll
  for (int i = 1; i < NLEV; ++i) if (rt * TM >= starts[i]) v = i;

  const int tid = threadIdx.x;
  const int lane = tid & 63, wave = tid >> 6;
  const int wm = (wave >> 2) * 64, wn = (wave & 3) * 64;
  const int fm = lane & 15;
  const int cb = lane >> 4;

  // A staging: 4 threads per row, 8 floats (one 16B bf16 chunk) each
  const int ar = tid >> 2;       // 0..127
  const int ah = tid & 3;        // chunk 0..3
  int prow = perm[rt * TM + ar];
  if (prow < 0) prow = 0;
  const float* xrow = x + (size_t)prow * D + ah * 8;
  const int sw = (ar >> 1) & 3;
  const int aslot = ar * BK + ((ah ^ sw) << 3);

  const u16* wb = weff + ((size_t)v * D + ct * TN) * D;
  // B staging source addresses (two 16B chunks per thread), swizzled at source
  const int c0i = wave * 64 + lane;            // chunk id = n*4 + slot
  const int c1i = 512 + c0i;
  const int n0 = c0i >> 2, s0 = c0i & 3, kc0 = s0 ^ ((n0 >> 1) & 3);
  const int n1 = c1i >> 2, s1 = c1i & 3, kc1 = s1 ^ ((n1 >> 1) & 3);
  const u16* gb0 = wb + n0 * D + kc0 * 8;
  const u16* gb1 = wb + n1 * D + kc1 * 8;
  const int bdst0 = c0i * 8, bdst1 = c1i * 8;

  f32x4 acc[4][4];
  #pragma unroll
  for (int i = 0; i < 4; ++i)
    #pragma unroll
    for (int j = 0; j < 4; ++j) acc[i][j] = (f32x4){0.f, 0.f, 0.f, 0.f};

  // ---- prologue: A(0) staged direct; x FIFO holds steps 1,2; B steps 0,1 ---
  {
    const f32x4* xp = (const f32x4*)xrow;
    f32x4 f0 = xp[0], f1 = xp[1];
    u16x8 cc;
    #pragma unroll
    for (int q = 0; q < 4; ++q) { cc[q] = f2bf(f0[q]); cc[4 + q] = f2bf(f1[q]); }
    *(u16x8*)(As[0] + aslot) = cc;
  }
  f32x4 p0a, p0b;   // x data for step i+1 (written at iter i)
  f32x4 p1a, p1b;   // x data for step i+2 (written at iter i+1)
  {
    const f32x4* xp = (const f32x4*)(xrow + BK);
    p0a = xp[0]; p0b = xp[1];
    const f32x4* xq = (const f32x4*)(xrow + 2 * BK);
    p1a = xq[0]; p1b = xq[1];
  }
  __builtin_amdgcn_global_load_lds(
      (const __attribute__((address_space(1))) void*)gb0,
      (__attribute__((address_space(3))) void*)(Bs[0] + bdst0), 16, 0, 0);
  __builtin_amdgcn_global_load_lds(
      (const __attribute__((address_space(1))) void*)gb1,
      (__attribute__((address_space(3))) void*)(Bs[0] + bdst1), 16, 0, 0);
  __builtin_amdgcn_global_load_lds(
      (const __attribute__((address_space(1))) void*)(gb0 + BK),
      (__attribute__((address_space(3))) void*)(Bs[1] + bdst0), 16, 0, 0);
  __builtin_amdgcn_global_load_lds(
      (const __attribute__((address_space(1))) void*)(gb1 + BK),
      (__attribute__((address_space(3))) void*)(Bs[1] + bdst1), 16, 0, 0);
  // one-time full drain (intrinsic issue order in this region not guaranteed)
  asm volatile("s_waitcnt vmcnt(0)" ::: "memory");
  asm volatile("s_waitcnt lgkmcnt(0)" ::: "memory");
  __builtin_amdgcn_s_barrier();
  __builtin_amdgcn_sched_barrier(0);

  #pragma unroll
  for (int i = 0; i < NITER; ++i) {
    // (1) issue B prefetch for step i+2 into Bs[(i+2)%3] -- FIRST in FIFO
    if (i + 2 < NITER) {
      const int ko = (i + 2) * BK;
      __builtin_amdgcn_global_load_lds(
          (const __attribute__((address_space(1))) void*)(gb0 + ko),
          (__attribute__((address_space(3))) void*)(Bs[(i + 2) % 3] + bdst0), 16, 0, 0);
      __builtin_amdgcn_global_load_lds(
          (const __attribute__((address_space(1))) void*)(gb1 + ko),
          (__attribute__((address_space(3))) void*)(Bs[(i + 2) % 3] + bdst1), 16, 0, 0);
    }
    asm volatile("" ::: "memory");   // pin FIFO order: B(i) before x(i)
    // (2) issue x loads for step i+3 (2-iter slack to their ds_write)
    f32x4 na, nb;
    if (i + 3 < NITER) {
      const f32x4* xp = (const f32x4*)(xrow + (i + 3) * BK);
      na = xp[0]; nb = xp[1];
    }
    // (3) compute on buffer i%3 (B landed: counted wait + barrier last iter)
    s16x8 af[4], bf[4];
    #pragma unroll
    for (int t4 = 0; t4 < 4; ++t4) {
      const int m = wm + t4 * 16 + fm;
      af[t4] = *(const s16x8*)(As[i % 3] + m * BK + ((cb ^ ((m >> 1) & 3)) << 3));
      const int n = wn + t4 * 16 + fm;
      bf[t4] = *(const s16x8*)(Bs[i % 3] + n * BK + ((cb ^ ((n >> 1) & 3)) << 3));
    }
    __builtin_amdgcn_s_setprio(1);
    #pragma unroll
    for (int tm = 0; tm < 4; ++tm)
      #pragma unroll
      for (int tn = 0; tn < 4; ++tn)
        acc[tm][tn] = __builtin_amdgcn_mfma_f32_16x16x32_bf16(af[tm], bf[tn], acc[tm][tn], 0, 0, 0);
    __builtin_amdgcn_s_setprio(0);
    if (i + 1 < NITER) {
      // (4) f2bf + ds_write A(i+1): data loaded at iter i-2 (2 iters of slack)
      u16x8 cc;
      #pragma unroll
      for (int q = 0; q < 4; ++q) { cc[q] = f2bf(p0a[q]); cc[4 + q] = f2bf(p0b[q]); }
      *(u16x8*)(As[(i + 1) % 3] + aslot) = cc;
      p0a = p1a; p0b = p1b;
      if (i + 3 < NITER) { p1a = na; p1b = nb; }
      // (5) counted pre-barrier wait: drain exactly B(i-1) (data for step i+1).
      // Ops newer than B(i-1): x(i-1)x2, B(i)x2, x(i)x2 -> keep 6 in steady
      // state; tail tapers as issues stop (i=13: keep 4; i=14: keep 0).
      if (i <= NITER - 4)      asm volatile("s_waitcnt vmcnt(6)" ::: "memory");
      else if (i == NITER - 3) asm volatile("s_waitcnt vmcnt(4)" ::: "memory");
      else                     asm volatile("s_waitcnt vmcnt(0)" ::: "memory");
      asm volatile("s_waitcnt lgkmcnt(0)" ::: "memory");
      __builtin_amdgcn_s_barrier();
      __builtin_amdgcn_sched_barrier(0);
    }
  }

  // Epilogue: C frag col=lane&15, row=(lane>>4)*4+reg; scatter rows via perm
  float bv[4];
  #pragma unroll
  for (int tn = 0; tn < 4; ++tn) bv[tn] = bias[ct * TN + wn + tn * 16 + fm];
  #pragma unroll
  for (int tm = 0; tm < 4; ++tm) {
    #pragma unroll
    for (int r = 0; r < 4; ++r) {
      const int mrow = wm + tm * 16 + (lane >> 4) * 4 + r;
      const int p2 = perm[rt * TM + mrow];
      if (p2 >= 0) {
        float* o = out + (size_t)p2 * D + ct * TN + wn + fm;
        #pragma unroll
        for (int tn = 0; tn < 4; ++tn)
          o[tn * 16] = acc[tm][tn][r] + bv[tn];
      }
    }
  }
}

extern "C" void kernel_launch(void* const* d_in, const int* in_sizes, int n_in,
                              void* d_out, int out_size, void* d_ws, size_t ws_size,
                              hipStream_t stream) {
  const float* x    = (const float*)d_in[0];
  const int*   val  = (const int*)d_in[1];
  const float* W    = (const float*)d_in[2];
  const float* lg   = (const float*)d_in[3];
  const float* attn = (const float*)d_in[4];
  const float* bias = (const float*)d_in[5];
  float* out = (float*)d_out;

  char* ws = (char*)d_ws;
  int* starts = (int*)(ws + 0);          // 11 ints
  u16* hist   = (u16*)(ws + 64);         // 128*10 u16
  int* perm   = (int*)(ws + 2688);       // 34048 ints -> ends 138880
  u16* weff   = (u16*)(ws + 139264);     // 10*512*512 bf16 = 5.24 MB

  k1<<<DD / 256 + NHB, 256, 0, stream>>>(W, lg, attn, val, weff, hist, perm);
  k2<<<NHB, 256, 0, stream>>>(val, hist, perm, starts);
  k3<<<dim3(D / TN, MAX_RT), 512, 0, stream>>>(x, weff, perm, starts, bias, out);
}